// Round 1
// baseline (1463.310 us; speedup 1.0000x reference)
//
#include <hip/hip_runtime.h>

constexpr int NFEAT = 256;
constexpr int NHID  = 128;

// ---------------- CSR build ----------------

__global__ void hist_kernel(const int* __restrict__ rows, int* __restrict__ cnt, int n) {
  int i = blockIdx.x * blockDim.x + threadIdx.x;
  if (i < n) atomicAdd(&cnt[rows[i]], 1);
}

// single-block exclusive scan over n counts -> row_ptr[0..n], also fills cursor
__global__ void scan_kernel(const int* __restrict__ cnt, int* __restrict__ row_ptr,
                            int* __restrict__ cursor, int n) {
  __shared__ int tmp[1024];
  __shared__ int carry_s;
  int tid = threadIdx.x;
  if (tid == 0) carry_s = 0;
  __syncthreads();
  for (int base = 0; base < n; base += 1024) {
    int i = base + tid;
    int v = (i < n) ? cnt[i] : 0;
    tmp[tid] = v;
    __syncthreads();
    #pragma unroll
    for (int off = 1; off < 1024; off <<= 1) {
      int t = (tid >= off) ? tmp[tid - off] : 0;
      __syncthreads();
      tmp[tid] += t;
      __syncthreads();
    }
    int incl = tmp[tid] + carry_s;
    int excl = incl - v;
    if (i < n) { row_ptr[i] = excl; cursor[i] = excl; }
    if (i == n - 1) row_ptr[n] = incl;
    __syncthreads();
    if (tid == 1023) carry_s = incl;
    __syncthreads();
  }
}

__global__ void scatter_kernel(const int* __restrict__ rows, const int* __restrict__ cols,
                               const float* __restrict__ vals, int* __restrict__ cursor,
                               int* __restrict__ cols_s, float* __restrict__ vals_s, int n) {
  int i = blockIdx.x * blockDim.x + threadIdx.x;
  if (i < n) {
    int p = atomicAdd(&cursor[rows[i]], 1);
    cols_s[p] = cols[i];
    vals_s[p] = vals[i];
  }
}

// ---------------- dense GEMM: C[M,128] = A[M,K] @ W[K,128] ----------------
// 256 threads, BM=64, BN=128, BK=32; each thread 8x4 outputs.

__global__ void gemm_kernel(const float* __restrict__ A, const float* __restrict__ W,
                            float* __restrict__ C, int M, int K) {
  __shared__ float As[64][33];
  __shared__ float Bs[32][128];
  int tid = threadIdx.x;
  int block_row = blockIdx.x * 64;
  int tx = tid & 31;   // col group: 32 groups x 4 cols
  int ty = tid >> 5;   // row group: 8 groups x 8 rows
  float acc[8][4];
  #pragma unroll
  for (int r = 0; r < 8; ++r)
    #pragma unroll
    for (int c = 0; c < 4; ++c) acc[r][c] = 0.f;

  for (int k0 = 0; k0 < K; k0 += 32) {
    // stage A tile 64x32 (float4 loads, 2 rows per thread)
    int ar  = tid >> 3;
    int acv = (tid & 7) * 4;
    #pragma unroll
    for (int half = 0; half < 2; ++half) {
      int rr = ar + half * 32;
      int grow = block_row + rr;
      float4 av = make_float4(0.f, 0.f, 0.f, 0.f);
      if (grow < M) av = *(const float4*)&A[(size_t)grow * K + k0 + acv];
      As[rr][acv + 0] = av.x; As[rr][acv + 1] = av.y;
      As[rr][acv + 2] = av.z; As[rr][acv + 3] = av.w;
    }
    // stage W tile 32x128 (float4 loads, 4 per thread)
    #pragma unroll
    for (int i = 0; i < 4; ++i) {
      int idx = tid + i * 256;          // float4 index 0..1023
      int brr = idx >> 5;
      int bcv = (idx & 31) * 4;
      *(float4*)&Bs[brr][bcv] = *(const float4*)&W[(size_t)(k0 + brr) * 128 + bcv];
    }
    __syncthreads();
    #pragma unroll
    for (int kk = 0; kk < 32; ++kk) {
      float4 b = *(const float4*)&Bs[kk][tx * 4];
      #pragma unroll
      for (int r = 0; r < 8; ++r) {
        float a = As[ty * 8 + r][kk];
        acc[r][0] += a * b.x; acc[r][1] += a * b.y;
        acc[r][2] += a * b.z; acc[r][3] += a * b.w;
      }
    }
    __syncthreads();
  }
  #pragma unroll
  for (int r = 0; r < 8; ++r) {
    int grow = block_row + ty * 8 + r;
    if (grow < M) {
      float4 v = make_float4(acc[r][0], acc[r][1], acc[r][2], acc[r][3]);
      *(float4*)&C[(size_t)grow * 128 + tx * 4] = v;
    }
  }
}

// ---------------- SpMM + bias + ReLU ----------------
// one 64-lane wave per output row; 2 f32 per lane across the 128 cols.

__global__ void spmm_kernel(const float* __restrict__ support, const int* __restrict__ row_ptr,
                            const int* __restrict__ cols, const float* __restrict__ vals,
                            const float* __restrict__ bias, float* __restrict__ out, int n_nodes) {
  int row  = blockIdx.x * (blockDim.x >> 6) + (threadIdx.x >> 6);
  int lane = threadIdx.x & 63;
  if (row >= n_nodes) return;
  int beg = row_ptr[row], end = row_ptr[row + 1];
  float acc0 = 0.f, acc1 = 0.f;
  for (int i = beg; i < end; ++i) {
    int c = cols[i];
    float v = vals[i];
    const float* s = support + (size_t)c * 128;
    acc0 += v * s[lane];
    acc1 += v * s[lane + 64];
  }
  size_t o = (size_t)row * 128;
  out[o + lane]      = fmaxf(acc0 + bias[lane], 0.f);
  out[o + lane + 64] = fmaxf(acc1 + bias[lane + 64], 0.f);
}

// ---------------- launch ----------------

extern "C" void kernel_launch(void* const* d_in, const int* in_sizes, int n_in,
                              void* d_out, int out_size, void* d_ws, size_t ws_size,
                              hipStream_t stream) {
  const float* x    = (const float*)d_in[0];
  const int*   erow = (const int*)d_in[1];
  const int*   ecol = (const int*)d_in[2];
  const float* evl  = (const float*)d_in[3];
  const float* W1   = (const float*)d_in[4];
  const float* b1   = (const float*)d_in[5];
  const float* W2   = (const float*)d_in[6];
  const float* b2   = (const float*)d_in[7];
  int n_nodes = in_sizes[0] / NFEAT;
  int n_edges = in_sizes[1];
  float* out = (float*)d_out;

  char* ws = (char*)d_ws;
  size_t off = 0;
  auto alloc = [&](size_t bytes) -> void* {
    void* p = ws + off;
    off += bytes;
    off = (off + 255) & ~(size_t)255;
    return p;
  };
  float* support = (float*)alloc((size_t)n_nodes * NHID * sizeof(float));
  int*   cnt     = (int*)alloc((size_t)n_nodes * sizeof(int));
  int*   row_ptr = (int*)alloc(((size_t)n_nodes + 1) * sizeof(int));
  int*   cursor  = (int*)alloc((size_t)n_nodes * sizeof(int));
  int*   cols_s  = (int*)alloc((size_t)n_edges * sizeof(int));
  float* vals_s  = (float*)alloc((size_t)n_edges * sizeof(float));

  // CSR build (shared by all 5 layers)
  hipMemsetAsync(cnt, 0, (size_t)n_nodes * sizeof(int), stream);
  hist_kernel<<<(n_edges + 255) / 256, 256, 0, stream>>>(erow, cnt, n_edges);
  scan_kernel<<<1, 1024, 0, stream>>>(cnt, row_ptr, cursor, n_nodes);
  scatter_kernel<<<(n_edges + 255) / 256, 256, 0, stream>>>(erow, ecol, evl, cursor,
                                                            cols_s, vals_s, n_edges);

  int gblocks = (n_nodes + 63) / 64;
  int sblocks = (n_nodes + 3) / 4;

  // layer 1: support = x @ W1 ; h = relu(spmm + b1) -> d_out
  gemm_kernel<<<gblocks, 256, 0, stream>>>(x, W1, support, n_nodes, NFEAT);
  spmm_kernel<<<sblocks, 256, 0, stream>>>(support, row_ptr, cols_s, vals_s, b1, out, n_nodes);

  // layers 2..5: shared W2
  for (int l = 0; l < 4; ++l) {
    gemm_kernel<<<gblocks, 256, 0, stream>>>(out, W2, support, n_nodes, NHID);
    spmm_kernel<<<sblocks, 256, 0, stream>>>(support, row_ptr, cols_s, vals_s, b2, out, n_nodes);
  }
}

// Round 2
// 1335.494 us; speedup vs baseline: 1.0957x; 1.0957x over previous
//
#include <hip/hip_runtime.h>

constexpr int NFEAT = 256;
constexpr int NHID  = 128;
constexpr int SCAN_B = 4096;   // elements per scan block (1024 threads x 4)

// ---------------- CSR build ----------------

__global__ void hist_kernel(const int* __restrict__ rows, int* __restrict__ cnt, int n) {
  int i = blockIdx.x * blockDim.x + threadIdx.x;
  if (i < n) atomicAdd(&cnt[rows[i]], 1);
}

// hierarchical scan: scan1 (per-block excl scan + block sums) -> scan2 (scan of
// block sums, tiny serial) -> scan3 (add block offsets, fill cursor + row_ptr[n])

__global__ void scan1_kernel(const int* __restrict__ cnt, int* __restrict__ part,
                             int* __restrict__ bsum, int n) {
  __shared__ int tmp[1024];
  int tid = threadIdx.x;
  int base = blockIdx.x * SCAN_B + tid * 4;
  int4 v = make_int4(0, 0, 0, 0);
  if (base + 4 <= n) {
    v = *(const int4*)&cnt[base];
  } else {
    if (base + 0 < n) v.x = cnt[base + 0];
    if (base + 1 < n) v.y = cnt[base + 1];
    if (base + 2 < n) v.z = cnt[base + 2];
    if (base + 3 < n) v.w = cnt[base + 3];
  }
  int s = v.x + v.y + v.z + v.w;
  tmp[tid] = s;
  __syncthreads();
  for (int off = 1; off < 1024; off <<= 1) {
    int t = (tid >= off) ? tmp[tid - off] : 0;
    __syncthreads();
    tmp[tid] += t;
    __syncthreads();
  }
  int excl = tmp[tid] - s;
  if (base + 0 < n) part[base + 0] = excl;
  if (base + 1 < n) part[base + 1] = excl + v.x;
  if (base + 2 < n) part[base + 2] = excl + v.x + v.y;
  if (base + 3 < n) part[base + 3] = excl + v.x + v.y + v.z;
  if (tid == 1023) bsum[blockIdx.x] = tmp[1023];
}

__global__ void scan2_kernel(int* __restrict__ bsum, int nb) {
  if (threadIdx.x == 0 && blockIdx.x == 0) {
    int run = 0;
    for (int i = 0; i < nb; ++i) { int t = bsum[i]; bsum[i] = run; run += t; }
    bsum[nb] = run;
  }
}

__global__ void scan3_kernel(int* __restrict__ row_ptr, const int* __restrict__ bsum,
                             int* __restrict__ cursor, int n, int nb) {
  int i = blockIdx.x * blockDim.x + threadIdx.x;
  if (i < n) {
    int v = row_ptr[i] + bsum[i / SCAN_B];
    row_ptr[i] = v;
    cursor[i]  = v;
  }
  if (i == 0) row_ptr[n] = bsum[nb];
}

__global__ void scatter_kernel(const int* __restrict__ rows, const int* __restrict__ cols,
                               const float* __restrict__ vals, int* __restrict__ cursor,
                               int* __restrict__ cols_s, float* __restrict__ vals_s, int n) {
  int i = blockIdx.x * blockDim.x + threadIdx.x;
  if (i < n) {
    int p = atomicAdd(&cursor[rows[i]], 1);
    cols_s[p] = cols[i];
    vals_s[p] = vals[i];
  }
}

// ---------------- dense GEMM: C[M,128] = A[M,K] @ W[K,128] ----------------
// 256 threads, BM=128, BN=128, BK=32; each thread 8x8 outputs (split 4+4 so
// LDS reads are 2-way-bank-aliased at worst, which is free on CDNA4).

__global__ __launch_bounds__(256) void gemm_kernel(const float* __restrict__ A,
                                                   const float* __restrict__ W,
                                                   float* __restrict__ C, int M, int K) {
  __shared__ float As[32][132];   // [k][row], pad 132 keeps 16B alignment of rows
  __shared__ float Bs[32][128];   // [k][col]
  int tid = threadIdx.x;
  int block_row = blockIdx.x * 128;
  int r8 = tid >> 4;   // 0..15  row group
  int c8 = tid & 15;   // 0..15  col group
  float acc[2][2][4][4] = {};     // [rh][ch][i][j]

  for (int k0 = 0; k0 < K; k0 += 32) {
    // stage A: 128 rows x 32 k, transposed into As[k][row]
    #pragma unroll
    for (int i = 0; i < 4; ++i) {
      int f = tid + i * 256;          // 0..1023 float4 slots
      int row = f >> 3;
      int kq = (f & 7) * 4;
      int grow = block_row + row;
      float4 av = make_float4(0.f, 0.f, 0.f, 0.f);
      if (grow < M) av = *(const float4*)&A[(size_t)grow * K + k0 + kq];
      As[kq + 0][row] = av.x; As[kq + 1][row] = av.y;
      As[kq + 2][row] = av.z; As[kq + 3][row] = av.w;
    }
    // stage B: 32 k x 128 cols (direct float4 copy)
    #pragma unroll
    for (int i = 0; i < 4; ++i) {
      int f = tid + i * 256;
      int r = f >> 5;
      int cq = (f & 31) * 4;
      *(float4*)&Bs[r][cq] = *(const float4*)&W[(size_t)(k0 + r) * 128 + cq];
    }
    __syncthreads();
    #pragma unroll
    for (int kk = 0; kk < 32; ++kk) {
      float4 a0 = *(const float4*)&As[kk][r8 * 4];
      float4 a1 = *(const float4*)&As[kk][r8 * 4 + 64];
      float4 b0 = *(const float4*)&Bs[kk][c8 * 4];
      float4 b1 = *(const float4*)&Bs[kk][c8 * 4 + 64];
      float ar[2][4] = {{a0.x, a0.y, a0.z, a0.w}, {a1.x, a1.y, a1.z, a1.w}};
      float br[2][4] = {{b0.x, b0.y, b0.z, b0.w}, {b1.x, b1.y, b1.z, b1.w}};
      #pragma unroll
      for (int rh = 0; rh < 2; ++rh)
        #pragma unroll
        for (int i = 0; i < 4; ++i)
          #pragma unroll
          for (int ch = 0; ch < 2; ++ch)
            #pragma unroll
            for (int j = 0; j < 4; ++j)
              acc[rh][ch][i][j] += ar[rh][i] * br[ch][j];
    }
    __syncthreads();
  }

  #pragma unroll
  for (int rh = 0; rh < 2; ++rh)
    #pragma unroll
    for (int i = 0; i < 4; ++i) {
      int grow = block_row + rh * 64 + r8 * 4 + i;
      if (grow < M) {
        #pragma unroll
        for (int ch = 0; ch < 2; ++ch) {
          float4 v = make_float4(acc[rh][ch][i][0], acc[rh][ch][i][1],
                                 acc[rh][ch][i][2], acc[rh][ch][i][3]);
          *(float4*)&C[(size_t)grow * 128 + ch * 64 + c8 * 4] = v;
        }
      }
    }
}

// ---------------- SpMM + bias + ReLU ----------------
// one 64-lane wave per output row; float2 per lane across the 128 cols.

__global__ void spmm_kernel(const float* __restrict__ support, const int* __restrict__ row_ptr,
                            const int* __restrict__ cols, const float* __restrict__ vals,
                            const float* __restrict__ bias, float* __restrict__ out, int n_nodes) {
  int row  = blockIdx.x * (blockDim.x >> 6) + (threadIdx.x >> 6);
  int lane = threadIdx.x & 63;
  if (row >= n_nodes) return;
  int beg = row_ptr[row], end = row_ptr[row + 1];
  float accx = 0.f, accy = 0.f;
  for (int i = beg; i < end; ++i) {
    int c = cols[i];
    float v = vals[i];
    float2 s = *(const float2*)&support[(size_t)c * 128 + lane * 2];
    accx += v * s.x;
    accy += v * s.y;
  }
  float2 b = *(const float2*)&bias[lane * 2];
  float2 o = make_float2(fmaxf(accx + b.x, 0.f), fmaxf(accy + b.y, 0.f));
  *(float2*)&out[(size_t)row * 128 + lane * 2] = o;
}

// ---------------- launch ----------------

extern "C" void kernel_launch(void* const* d_in, const int* in_sizes, int n_in,
                              void* d_out, int out_size, void* d_ws, size_t ws_size,
                              hipStream_t stream) {
  const float* x    = (const float*)d_in[0];
  const int*   erow = (const int*)d_in[1];
  const int*   ecol = (const int*)d_in[2];
  const float* evl  = (const float*)d_in[3];
  const float* W1   = (const float*)d_in[4];
  const float* b1   = (const float*)d_in[5];
  const float* W2   = (const float*)d_in[6];
  const float* b2   = (const float*)d_in[7];
  int n_nodes = in_sizes[0] / NFEAT;
  int n_edges = in_sizes[1];
  float* out = (float*)d_out;

  char* ws = (char*)d_ws;
  size_t off = 0;
  auto alloc = [&](size_t bytes) -> void* {
    void* p = ws + off;
    off += bytes;
    off = (off + 255) & ~(size_t)255;
    return p;
  };
  float* support = (float*)alloc((size_t)n_nodes * NHID * sizeof(float));
  int*   cnt     = (int*)alloc((size_t)n_nodes * sizeof(int));
  int*   row_ptr = (int*)alloc(((size_t)n_nodes + 1) * sizeof(int));
  int*   cursor  = (int*)alloc((size_t)n_nodes * sizeof(int));
  int*   cols_s  = (int*)alloc((size_t)n_edges * sizeof(int));
  float* vals_s  = (float*)alloc((size_t)n_edges * sizeof(float));
  int nb = (n_nodes + SCAN_B - 1) / SCAN_B;
  int*   bsum    = (int*)alloc((size_t)(nb + 1) * sizeof(int));

  // CSR build (shared by all 5 layers)
  hipMemsetAsync(cnt, 0, (size_t)n_nodes * sizeof(int), stream);
  hist_kernel<<<(n_edges + 255) / 256, 256, 0, stream>>>(erow, cnt, n_edges);
  scan1_kernel<<<nb, 1024, 0, stream>>>(cnt, row_ptr, bsum, n_nodes);
  scan2_kernel<<<1, 64, 0, stream>>>(bsum, nb);
  scan3_kernel<<<(n_nodes + 255) / 256, 256, 0, stream>>>(row_ptr, bsum, cursor, n_nodes, nb);
  scatter_kernel<<<(n_edges + 255) / 256, 256, 0, stream>>>(erow, ecol, evl, cursor,
                                                            cols_s, vals_s, n_edges);

  int gblocks = (n_nodes + 127) / 128;
  int sblocks = (n_nodes + 3) / 4;

  // layer 1: support = x @ W1 ; h = relu(spmm + b1) -> d_out
  gemm_kernel<<<gblocks, 256, 0, stream>>>(x, W1, support, n_nodes, NFEAT);
  spmm_kernel<<<sblocks, 256, 0, stream>>>(support, row_ptr, cols_s, vals_s, b1, out, n_nodes);

  // layers 2..5: shared W2
  for (int l = 0; l < 4; ++l) {
    gemm_kernel<<<gblocks, 256, 0, stream>>>(out, W2, support, n_nodes, NHID);
    spmm_kernel<<<sblocks, 256, 0, stream>>>(support, row_ptr, cols_s, vals_s, b2, out, n_nodes);
  }
}

// Round 3
// 1078.300 us; speedup vs baseline: 1.3571x; 1.2385x over previous
//
#include <hip/hip_runtime.h>

constexpr int NFEAT = 256;
constexpr int NHID  = 128;
constexpr int SCAN_B = 4096;   // elements per scan block (1024 threads x 4)

// ---------------- CSR build ----------------

__global__ void hist_kernel(const int* __restrict__ rows, int* __restrict__ cnt, int n) {
  int i = blockIdx.x * blockDim.x + threadIdx.x;
  if (i < n) atomicAdd(&cnt[rows[i]], 1);
}

__global__ void scan1_kernel(const int* __restrict__ cnt, int* __restrict__ part,
                             int* __restrict__ bsum, int n) {
  __shared__ int tmp[1024];
  int tid = threadIdx.x;
  int base = blockIdx.x * SCAN_B + tid * 4;
  int4 v = make_int4(0, 0, 0, 0);
  if (base + 4 <= n) {
    v = *(const int4*)&cnt[base];
  } else {
    if (base + 0 < n) v.x = cnt[base + 0];
    if (base + 1 < n) v.y = cnt[base + 1];
    if (base + 2 < n) v.z = cnt[base + 2];
    if (base + 3 < n) v.w = cnt[base + 3];
  }
  int s = v.x + v.y + v.z + v.w;
  tmp[tid] = s;
  __syncthreads();
  for (int off = 1; off < 1024; off <<= 1) {
    int t = (tid >= off) ? tmp[tid - off] : 0;
    __syncthreads();
    tmp[tid] += t;
    __syncthreads();
  }
  int excl = tmp[tid] - s;
  if (base + 0 < n) part[base + 0] = excl;
  if (base + 1 < n) part[base + 1] = excl + v.x;
  if (base + 2 < n) part[base + 2] = excl + v.x + v.y;
  if (base + 3 < n) part[base + 3] = excl + v.x + v.y + v.z;
  if (tid == 1023) bsum[blockIdx.x] = tmp[1023];
}

__global__ void scan2_kernel(int* __restrict__ bsum, int nb) {
  if (threadIdx.x == 0 && blockIdx.x == 0) {
    int run = 0;
    for (int i = 0; i < nb; ++i) { int t = bsum[i]; bsum[i] = run; run += t; }
    bsum[nb] = run;
  }
}

__global__ void scan3_kernel(int* __restrict__ row_ptr, const int* __restrict__ bsum,
                             int* __restrict__ cursor, int n, int nb) {
  int i = blockIdx.x * blockDim.x + threadIdx.x;
  if (i < n) {
    int v = row_ptr[i] + bsum[i / SCAN_B];
    row_ptr[i] = v;
    cursor[i]  = v;
  }
  if (i == 0) row_ptr[n] = bsum[nb];
}

__global__ void scatter_kernel(const int* __restrict__ rows, const int* __restrict__ cols,
                               const float* __restrict__ vals, int* __restrict__ cursor,
                               int* __restrict__ cols_s, float* __restrict__ vals_s, int n) {
  int i = blockIdx.x * blockDim.x + threadIdx.x;
  if (i < n) {
    int p = atomicAdd(&cursor[rows[i]], 1);
    cols_s[p] = cols[i];
    vals_s[p] = vals[i];
  }
}

// ---------------- dense GEMM: C[M,128] = A[M,K] @ W[K,128] ----------------
// 256 threads, BM=128, BN=128, BK=32; each thread 8x8 outputs.

__global__ __launch_bounds__(256) void gemm_kernel(const float* __restrict__ A,
                                                   const float* __restrict__ W,
                                                   float* __restrict__ C, int M, int K) {
  __shared__ float As[32][132];
  __shared__ float Bs[32][128];
  int tid = threadIdx.x;
  int block_row = blockIdx.x * 128;
  int r8 = tid >> 4;   // 0..15
  int c8 = tid & 15;   // 0..15
  float acc[2][2][4][4] = {};

  for (int k0 = 0; k0 < K; k0 += 32) {
    #pragma unroll
    for (int i = 0; i < 4; ++i) {
      int f = tid + i * 256;
      int row = f >> 3;
      int kq = (f & 7) * 4;
      int grow = block_row + row;
      float4 av = make_float4(0.f, 0.f, 0.f, 0.f);
      if (grow < M) av = *(const float4*)&A[(size_t)grow * K + k0 + kq];
      As[kq + 0][row] = av.x; As[kq + 1][row] = av.y;
      As[kq + 2][row] = av.z; As[kq + 3][row] = av.w;
    }
    #pragma unroll
    for (int i = 0; i < 4; ++i) {
      int f = tid + i * 256;
      int r = f >> 5;
      int cq = (f & 31) * 4;
      *(float4*)&Bs[r][cq] = *(const float4*)&W[(size_t)(k0 + r) * 128 + cq];
    }
    __syncthreads();
    #pragma unroll
    for (int kk = 0; kk < 32; ++kk) {
      float4 a0 = *(const float4*)&As[kk][r8 * 4];
      float4 a1 = *(const float4*)&As[kk][r8 * 4 + 64];
      float4 b0 = *(const float4*)&Bs[kk][c8 * 4];
      float4 b1 = *(const float4*)&Bs[kk][c8 * 4 + 64];
      float ar[2][4] = {{a0.x, a0.y, a0.z, a0.w}, {a1.x, a1.y, a1.z, a1.w}};
      float br[2][4] = {{b0.x, b0.y, b0.z, b0.w}, {b1.x, b1.y, b1.z, b1.w}};
      #pragma unroll
      for (int rh = 0; rh < 2; ++rh)
        #pragma unroll
        for (int i = 0; i < 4; ++i)
          #pragma unroll
          for (int ch = 0; ch < 2; ++ch)
            #pragma unroll
            for (int j = 0; j < 4; ++j)
              acc[rh][ch][i][j] += ar[rh][i] * br[ch][j];
    }
    __syncthreads();
  }

  #pragma unroll
  for (int rh = 0; rh < 2; ++rh)
    #pragma unroll
    for (int i = 0; i < 4; ++i) {
      int grow = block_row + rh * 64 + r8 * 4 + i;
      if (grow < M) {
        #pragma unroll
        for (int ch = 0; ch < 2; ++ch) {
          float4 v = make_float4(acc[rh][ch][i][0], acc[rh][ch][i][1],
                                 acc[rh][ch][i][2], acc[rh][ch][i][3]);
          *(float4*)&C[(size_t)grow * 128 + ch * 64 + c8 * 4] = v;
        }
      }
    }
}

// ---------------- SpMM + bias + ReLU ----------------
// one 64-lane wave per output row. Lane l preloads edge (beg+l)'s col/val in
// ONE coalesced load for the whole row; per-edge values come from __shfl
// broadcast (register, no memory dep). Gathers are then independent ->
// unroll x4 keeps 4+ outstanding 512B gathers per wave (latency -> bandwidth).

__global__ void spmm_kernel(const float* __restrict__ support, const int* __restrict__ row_ptr,
                            const int* __restrict__ cols, const float* __restrict__ vals,
                            const float* __restrict__ bias, float* __restrict__ out, int n_nodes) {
  int row  = blockIdx.x * (blockDim.x >> 6) + (threadIdx.x >> 6);
  int lane = threadIdx.x & 63;
  if (row >= n_nodes) return;
  int beg = row_ptr[row], end = row_ptr[row + 1];
  float accx = 0.f, accy = 0.f;
  for (int chunk = beg; chunk < end; chunk += 64) {
    int idx = chunk + lane;
    int m = min(64, end - chunk);
    int cl = (idx < end) ? cols[idx] : 0;
    float vl = (idx < end) ? vals[idx] : 0.f;
    int e = 0;
    for (; e + 4 <= m; e += 4) {
      int c0 = __shfl(cl, e),     c1 = __shfl(cl, e + 1);
      int c2 = __shfl(cl, e + 2), c3 = __shfl(cl, e + 3);
      float v0 = __shfl(vl, e),     v1 = __shfl(vl, e + 1);
      float v2 = __shfl(vl, e + 2), v3 = __shfl(vl, e + 3);
      float2 s0 = *(const float2*)&support[(size_t)c0 * 128 + lane * 2];
      float2 s1 = *(const float2*)&support[(size_t)c1 * 128 + lane * 2];
      float2 s2 = *(const float2*)&support[(size_t)c2 * 128 + lane * 2];
      float2 s3 = *(const float2*)&support[(size_t)c3 * 128 + lane * 2];
      accx += v0 * s0.x; accy += v0 * s0.y;
      accx += v1 * s1.x; accy += v1 * s1.y;
      accx += v2 * s2.x; accy += v2 * s2.y;
      accx += v3 * s3.x; accy += v3 * s3.y;
    }
    for (; e < m; ++e) {
      int ce = __shfl(cl, e);
      float ve = __shfl(vl, e);
      float2 s = *(const float2*)&support[(size_t)ce * 128 + lane * 2];
      accx += ve * s.x; accy += ve * s.y;
    }
  }
  float2 b = *(const float2*)&bias[lane * 2];
  float2 o = make_float2(fmaxf(accx + b.x, 0.f), fmaxf(accy + b.y, 0.f));
  *(float2*)&out[(size_t)row * 128 + lane * 2] = o;
}

// ---------------- launch ----------------

extern "C" void kernel_launch(void* const* d_in, const int* in_sizes, int n_in,
                              void* d_out, int out_size, void* d_ws, size_t ws_size,
                              hipStream_t stream) {
  const float* x    = (const float*)d_in[0];
  const int*   erow = (const int*)d_in[1];
  const int*   ecol = (const int*)d_in[2];
  const float* evl  = (const float*)d_in[3];
  const float* W1   = (const float*)d_in[4];
  const float* b1   = (const float*)d_in[5];
  const float* W2   = (const float*)d_in[6];
  const float* b2   = (const float*)d_in[7];
  int n_nodes = in_sizes[0] / NFEAT;
  int n_edges = in_sizes[1];
  float* out = (float*)d_out;

  char* ws = (char*)d_ws;
  size_t off = 0;
  auto alloc = [&](size_t bytes) -> void* {
    void* p = ws + off;
    off += bytes;
    off = (off + 255) & ~(size_t)255;
    return p;
  };
  float* support = (float*)alloc((size_t)n_nodes * NHID * sizeof(float));
  int*   cnt     = (int*)alloc((size_t)n_nodes * sizeof(int));
  int*   row_ptr = (int*)alloc(((size_t)n_nodes + 1) * sizeof(int));
  int*   cursor  = (int*)alloc((size_t)n_nodes * sizeof(int));
  int*   cols_s  = (int*)alloc((size_t)n_edges * sizeof(int));
  float* vals_s  = (float*)alloc((size_t)n_edges * sizeof(float));
  int nb = (n_nodes + SCAN_B - 1) / SCAN_B;
  int*   bsum    = (int*)alloc((size_t)(nb + 1) * sizeof(int));

  // CSR build (shared by all 5 layers)
  hipMemsetAsync(cnt, 0, (size_t)n_nodes * sizeof(int), stream);
  hist_kernel<<<(n_edges + 255) / 256, 256, 0, stream>>>(erow, cnt, n_edges);
  scan1_kernel<<<nb, 1024, 0, stream>>>(cnt, row_ptr, bsum, n_nodes);
  scan2_kernel<<<1, 64, 0, stream>>>(bsum, nb);
  scan3_kernel<<<(n_nodes + 255) / 256, 256, 0, stream>>>(row_ptr, bsum, cursor, n_nodes, nb);
  scatter_kernel<<<(n_edges + 255) / 256, 256, 0, stream>>>(erow, ecol, evl, cursor,
                                                            cols_s, vals_s, n_edges);

  int gblocks = (n_nodes + 127) / 128;
  int sblocks = (n_nodes + 3) / 4;

  gemm_kernel<<<gblocks, 256, 0, stream>>>(x, W1, support, n_nodes, NFEAT);
  spmm_kernel<<<sblocks, 256, 0, stream>>>(support, row_ptr, cols_s, vals_s, b1, out, n_nodes);

  for (int l = 0; l < 4; ++l) {
    gemm_kernel<<<gblocks, 256, 0, stream>>>(out, W2, support, n_nodes, NHID);
    spmm_kernel<<<sblocks, 256, 0, stream>>>(support, row_ptr, cols_s, vals_s, b2, out, n_nodes);
  }
}